// Round 1
// baseline (108.185 us; speedup 1.0000x reference)
//
#include <hip/hip_runtime.h>
#include <math.h>

namespace {
constexpr int V = 2;
constexpr int B = 16384;
constexpr int C = 100;
constexpr int D = 512;
constexpr float MARGIN = 10.0f;
constexpr float EPS = 1e-8f;
constexpr int ROWS_PER_BLOCK = 4;               // 4 waves/block, 1 row/wave
constexpr int NBLOCKS = (V * B) / ROWS_PER_BLOCK; // 8192
}

// One 64-lane wave per (v,b) row: 4 simultaneous length-512 reductions.
// Lane i reads float4 at d = 4i and d = 256+4i -> perfectly coalesced.
__global__ __launch_bounds__(256) void row_kernel(
    const float* __restrict__ feat, const int* __restrict__ label,
    const float* __restrict__ anchor, float* __restrict__ sims,
    float* __restrict__ partials)
{
    const int wave = threadIdx.x >> 6;
    const int lane = threadIdx.x & 63;
    const int row  = blockIdx.x * ROWS_PER_BLOCK + wave;   // row = v*B + b
    const int v = row >> 14;          // / B  (B = 16384)
    const int b = row & (B - 1);
    const float* frow = feat + (size_t)row * D;
    const float* crow = anchor + ((size_t)v * C + label[b]) * D;

    float s_ff = 0.f, s_cc = 0.f, s_fc = 0.f, s_dd = 0.f;
#pragma unroll
    for (int h = 0; h < 2; ++h) {
        const int d = h * 256 + lane * 4;
        const float4 f = *reinterpret_cast<const float4*>(frow + d);
        const float4 c = *reinterpret_cast<const float4*>(crow + d);
        s_ff += f.x*f.x + f.y*f.y + f.z*f.z + f.w*f.w;
        s_cc += c.x*c.x + c.y*c.y + c.z*c.z + c.w*c.w;
        s_fc += f.x*c.x + f.y*c.y + f.z*c.z + f.w*c.w;
        const float dx = f.x-c.x, dy = f.y-c.y, dz = f.z-c.z, dw = f.w-c.w;
        s_dd += dx*dx + dy*dy + dz*dz + dw*dw;
    }
#pragma unroll
    for (int off = 32; off; off >>= 1) {
        s_ff += __shfl_xor(s_ff, off);
        s_cc += __shfl_xor(s_cc, off);
        s_fc += __shfl_xor(s_fc, off);
        s_dd += __shfl_xor(s_dd, off);
    }
    __shared__ float blk[ROWS_PER_BLOCK];
    if (lane == 0) {
        const float fn = fmaxf(sqrtf(s_ff), EPS);
        const float cn = fmaxf(sqrtf(s_cc), EPS);
        sims[row] = s_fc / (fn * cn);
        blk[wave] = s_dd;
    }
    __syncthreads();
    if (threadIdx.x == 0)
        partials[blockIdx.x] = blk[0] + blk[1] + blk[2] + blk[3];
}

// inter_loss[v] via the closed form: sum_{c!=e} ||a_c-a_e||^2
//   = 2*C*S - 2*||m||^2, with S = sum a^2, m_d = sum_c a[c][d].
// One block per v; thread t owns dimension d = t.
__global__ __launch_bounds__(512) void inter_kernel(
    const float* __restrict__ anchor, float* __restrict__ inter_out)
{
    const int v = blockIdx.x;
    const int d = threadIdx.x;
    const float* a = anchor + (size_t)v * C * D;
    float m = 0.f, s = 0.f;
#pragma unroll 4
    for (int c = 0; c < C; ++c) {
        const float x = a[(size_t)c * D + d];
        m += x;
        s += x * x;
    }
    float mm = m * m;
#pragma unroll
    for (int off = 32; off; off >>= 1) {
        s  += __shfl_xor(s, off);
        mm += __shfl_xor(mm, off);
    }
    __shared__ float rs[8], rm[8];
    const int wave = threadIdx.x >> 6, lane = threadIdx.x & 63;
    if (lane == 0) { rs[wave] = s; rm[wave] = mm; }
    __syncthreads();
    if (threadIdx.x == 0) {
        float S = 0.f, MM = 0.f;
        for (int w = 0; w < 8; ++w) { S += rs[w]; MM += rm[w]; }
        const float inter = ((float)C * S - MM) / (float)(C * (C - 1));
        inter_out[v] = fmaxf(MARGIN - inter, 0.f);
    }
}

// Reduce the 8192 per-block diff^2 partials (4096 per v) + combine loss.
__global__ __launch_bounds__(1024) void finalize_kernel(
    const float* __restrict__ partials, const float* __restrict__ inter,
    float* __restrict__ out)
{
    const int vv = threadIdx.x >> 9;      // 0..1 -> which v-half
    const int t  = threadIdx.x & 511;
    float s = 0.f;
#pragma unroll
    for (int i = 0; i < 8; ++i)
        s += partials[vv * (NBLOCKS / 2) + t + i * 512];
    const int wave = threadIdx.x >> 6, lane = threadIdx.x & 63;
#pragma unroll
    for (int off = 32; off; off >>= 1) s += __shfl_xor(s, off);
    __shared__ float red[16];
    if (lane == 0) red[wave] = s;
    __syncthreads();
    if (threadIdx.x == 0) {
        float cl0 = 0.f, cl1 = 0.f;
        for (int w = 0; w < 8;  ++w) cl0 += red[w];
        for (int w = 8; w < 16; ++w) cl1 += red[w];
        // mean_v( sum_diff2_v / (2B) ) = (cl0+cl1) / (4B)
        const float center_mean = (cl0 + cl1) / (4.0f * (float)B);
        const float inter_mean  = 0.5f * (inter[0] + inter[1]);
        out[0] = center_mean + inter_mean;
    }
}

extern "C" void kernel_launch(void* const* d_in, const int* in_sizes, int n_in,
                              void* d_out, int out_size, void* d_ws, size_t ws_size,
                              hipStream_t stream)
{
    const float* feat   = (const float*)d_in[0];
    const int*   label  = (const int*)d_in[1];
    const float* anchor = (const float*)d_in[2];
    float* out      = (float*)d_out;      // [0] = loss, [1..32768] = sims
    float* ws       = (float*)d_ws;
    float* partials = ws;                 // NBLOCKS floats
    float* inter    = ws + NBLOCKS;       // V floats
    float* sims     = out + 1;

    hipLaunchKernelGGL(inter_kernel, dim3(V), dim3(512), 0, stream,
                       anchor, inter);
    hipLaunchKernelGGL(row_kernel, dim3(NBLOCKS), dim3(256), 0, stream,
                       feat, label, anchor, sims, partials);
    hipLaunchKernelGGL(finalize_kernel, dim3(1), dim3(1024), 0, stream,
                       partials, inter, out);
}

// Round 2
// 98.355 us; speedup vs baseline: 1.0999x; 1.0999x over previous
//
#include <hip/hip_runtime.h>
#include <math.h>

namespace {
constexpr int V = 2;
constexpr int B = 16384;
constexpr int C = 100;
constexpr int D = 512;
constexpr float MARGIN = 10.0f;
constexpr float EPS = 1e-8f;

constexpr int RB = 2048;            // row blocks (4 waves each, 4 rows/wave)
constexpr int ROWS_PER_WAVE = 4;    // 2048*4*4 = 32768 = V*B rows
constexpr int IB_PER_V = 8;         // inter chunk-blocks per v
constexpr int IB = V * IB_PER_V;    // 16
constexpr int CHUNK = 13;           // ceil(100/8)
// ws layout (floats): [0,RB) dd-partials | [RB,RB+IB) s-partials | [RB+IB, +IB*512) m-partials
}

__global__ __launch_bounds__(256) void main_kernel(
    const float* __restrict__ feat, const int* __restrict__ label,
    const float* __restrict__ anchor, float* __restrict__ sims,
    float* __restrict__ ws)
{
    __shared__ float blk[4];
    const int wave = threadIdx.x >> 6;
    const int lane = threadIdx.x & 63;

    if (blockIdx.x < RB) {
        // ---- per-row part: 1 wave handles 4 consecutive (v,b) rows ----
        const int wid = blockIdx.x * 4 + wave;           // 0..8191
        float s_dd = 0.f;
#pragma unroll
        for (int r = 0; r < ROWS_PER_WAVE; ++r) {
            const int row = wid * ROWS_PER_WAVE + r;     // row = v*B + b
            const int v = row >> 14;                     // / B
            const int b = row & (B - 1);
            const float* frow = feat + (size_t)row * D;
            const float* crow = anchor + ((size_t)v * C + label[b]) * D;
            float s_ff = 0.f, s_cc = 0.f, s_fc = 0.f;
#pragma unroll
            for (int h = 0; h < 2; ++h) {
                const int d = h * 256 + lane * 4;
                const float4 f = *reinterpret_cast<const float4*>(frow + d);
                const float4 c = *reinterpret_cast<const float4*>(crow + d);
                s_ff += f.x*f.x + f.y*f.y + f.z*f.z + f.w*f.w;
                s_cc += c.x*c.x + c.y*c.y + c.z*c.z + c.w*c.w;
                s_fc += f.x*c.x + f.y*c.y + f.z*c.z + f.w*c.w;
                const float dx = f.x-c.x, dy = f.y-c.y, dz = f.z-c.z, dw = f.w-c.w;
                s_dd += dx*dx + dy*dy + dz*dz + dw*dw;
            }
#pragma unroll
            for (int off = 32; off; off >>= 1) {
                s_ff += __shfl_xor(s_ff, off);
                s_cc += __shfl_xor(s_cc, off);
                s_fc += __shfl_xor(s_fc, off);
            }
            if (lane == 0) {
                const float fn = fmaxf(sqrtf(s_ff), EPS);
                const float cn = fmaxf(sqrtf(s_cc), EPS);
                sims[row] = s_fc / (fn * cn);
            }
        }
#pragma unroll
        for (int off = 32; off; off >>= 1) s_dd += __shfl_xor(s_dd, off);
        if (lane == 0) blk[wave] = s_dd;
        __syncthreads();
        if (threadIdx.x == 0)
            ws[blockIdx.x] = blk[0] + blk[1] + blk[2] + blk[3];
    } else {
        // ---- inter part: closed form, chunked over anchor rows ----
        const int ib = blockIdx.x - RB;                  // 0..15
        const int v = ib >> 3, chunk = ib & 7;
        const int c0 = chunk * CHUNK;
        const int c1 = (c0 + CHUNK < C) ? c0 + CHUNK : C;
        const float* a = anchor + (size_t)v * C * D;
        const int d0 = threadIdx.x, d1 = threadIdx.x + 256;
        float m0 = 0.f, m1 = 0.f, s = 0.f;
        for (int c = c0; c < c1; ++c) {
            const float x0 = a[(size_t)c * D + d0];
            const float x1 = a[(size_t)c * D + d1];
            m0 += x0; m1 += x1; s += x0*x0 + x1*x1;
        }
        float* im = ws + RB + IB;
        im[ib * D + d0] = m0;
        im[ib * D + d1] = m1;
#pragma unroll
        for (int off = 32; off; off >>= 1) s += __shfl_xor(s, off);
        if (lane == 0) blk[wave] = s;
        __syncthreads();
        if (threadIdx.x == 0)
            ws[RB + ib] = blk[0] + blk[1] + blk[2] + blk[3];
    }
}

// Single block: reduce dd-partials, chunked m-vectors, s-partials; emit loss.
__global__ __launch_bounds__(1024) void finalize_kernel(
    const float* __restrict__ ws, float* __restrict__ out)
{
    const float* partials = ws;
    const float* is = ws + RB;
    const float* im = ws + RB + IB;
    const int t = threadIdx.x;
    const int wave = t >> 6, lane = t & 63;

    float sdd = partials[t] + partials[t + 1024];

    const int v = t >> 9, d = t & 511;     // waves 0-7 -> v=0, 8-15 -> v=1
    float m = 0.f;
#pragma unroll
    for (int k = 0; k < IB_PER_V; ++k)
        m += im[((size_t)v * IB_PER_V + k) * D + d];
    float mm = m * m;

#pragma unroll
    for (int off = 32; off; off >>= 1) {
        sdd += __shfl_xor(sdd, off);
        mm  += __shfl_xor(mm, off);
    }
    __shared__ float rdd[16], rmm[16];
    if (lane == 0) { rdd[wave] = sdd; rmm[wave] = mm; }
    __syncthreads();
    if (t == 0) {
        float ddt = 0.f;
        for (int w = 0; w < 16; ++w) ddt += rdd[w];
        float MM0 = 0.f, MM1 = 0.f;
        for (int w = 0; w < 8;  ++w) MM0 += rmm[w];
        for (int w = 8; w < 16; ++w) MM1 += rmm[w];
        float S0 = 0.f, S1 = 0.f;
        for (int k = 0; k < IB_PER_V; ++k) { S0 += is[k]; S1 += is[IB_PER_V + k]; }
        const float denom = (float)(C * (C - 1));
        const float inter0 = ((float)C * S0 - MM0) / denom;
        const float inter1 = ((float)C * S1 - MM1) / denom;
        const float il = 0.5f * (fmaxf(MARGIN - inter0, 0.f) +
                                 fmaxf(MARGIN - inter1, 0.f));
        // mean_v( dd_v / (2B) ) = ddt / (4B)
        out[0] = ddt / (4.0f * (float)B) + il;
    }
}

extern "C" void kernel_launch(void* const* d_in, const int* in_sizes, int n_in,
                              void* d_out, int out_size, void* d_ws, size_t ws_size,
                              hipStream_t stream)
{
    const float* feat   = (const float*)d_in[0];
    const int*   label  = (const int*)d_in[1];
    const float* anchor = (const float*)d_in[2];
    float* out  = (float*)d_out;          // [0] = loss, [1..32768] = sims
    float* ws   = (float*)d_ws;
    float* sims = out + 1;

    hipLaunchKernelGGL(main_kernel, dim3(RB + IB), dim3(256), 0, stream,
                       feat, label, anchor, sims, ws);
    hipLaunchKernelGGL(finalize_kernel, dim3(1), dim3(1024), 0, stream,
                       ws, out);
}